// Round 4
// baseline (2707.789 us; speedup 1.0000x reference)
//
#include <hip/hip_runtime.h>

typedef unsigned int uint;
typedef unsigned short ushort;
typedef unsigned long long u64;
typedef __attribute__((ext_vector_type(8))) short bf16x8;
typedef __attribute__((ext_vector_type(4))) float f32x4;

// Problem constants
#define T_STEPS 512
#define BATCH   512
#define NB      8       // batch rows per replica
#define RD      16      // inter-stage ring depth (power of 2)
#define XS      168     // xh plane row stride (ushort)
#define CSTR    12      // c-ring pad: floats per (slot,sidx) row (16B aligned, 2-way banks)
#define OUTC    96

__device__ __forceinline__ ushort f2bf(float f){
  uint u = __builtin_bit_cast(uint, f);
  u = (u + 0x7FFFu + ((u >> 16) & 1u)) >> 16;   // RNE
  return (ushort)u;
}
__device__ __forceinline__ float bf2f(ushort h){
  uint u = ((uint)h) << 16; return __builtin_bit_cast(float, u);
}
__device__ __forceinline__ float sigm(float x){
  float e = __builtin_exp2f(-1.44269504f * x);
  return __builtin_amdgcn_rcpf(1.0f + e);
}
__device__ __forceinline__ float tanh_fast(float x){
  float e = __builtin_exp2f(-2.88539008f * x);
  return 2.0f * __builtin_amdgcn_rcpf(1.0f + e) - 1.0f;
}
// Relaxed agent-scope atomics: LLC-coherent, no L1/L2 invalidate/writeback.
__device__ __forceinline__ uint aload32(const uint* p){
  return __hip_atomic_load(p, __ATOMIC_RELAXED, __HIP_MEMORY_SCOPE_AGENT);
}
__device__ __forceinline__ void astore32(uint* p, uint v){
  __hip_atomic_store(p, v, __ATOMIC_RELAXED, __HIP_MEMORY_SCOPE_AGENT);
}
__device__ __forceinline__ u64 aload64(const u64* p){
  return __hip_atomic_load(p, __ATOMIC_RELAXED, __HIP_MEMORY_SCOPE_AGENT);
}
__device__ __forceinline__ void astore64(u64* p, u64 v){
  __hip_atomic_store(p, v, __ATOMIC_RELAXED, __HIP_MEMORY_SCOPE_AGENT);
}

// 4-stage pipeline (stage = blockIdx.x>>6, rep = blockIdx.x&63), NB=8 rows/block.
// Activations/hops carried as split-bf16 hi/lo planes (converted ONCE by the
// producer); GEMM inner loop is pure ds_read_b128 + MFMA. Hop payloads are
// prefetched into registers one step ahead (flag poll + data load latency
// hidden under GEMM/gates); producer flags deferred to next step's B1 where a
// single vmcnt(0) drains both prefetch loads and hop stores.
__global__ __launch_bounds__(512, 2)
void rnn_pipeline(const float* __restrict__ x,
                  const float* __restrict__ W0, const float* __restrict__ b0,
                  const float* __restrict__ W1, const float* __restrict__ b1,
                  const float* __restrict__ W2, const float* __restrict__ b2,
                  const float* __restrict__ W3, const float* __restrict__ b3,
                  const float* __restrict__ Wa, const float* __restrict__ ba,
                  float* __restrict__ y_out,
                  uint* __restrict__ prod, uint* __restrict__ consA,
                  uint* __restrict__ consB,
                  u64* __restrict__ hop0, u64* __restrict__ hop1,
                  u64* __restrict__ hop2)
{
  const int tid  = threadIdx.x;
  const int wv   = tid >> 6;      // wave 0..7
  const int lane = tid & 63;
  const int l15  = lane & 15;
  const int hi   = lane >> 4;     // 0..3
  const int rep  = blockIdx.x & 63;
  const int stage= blockIdx.x >> 6;
  const int b0r  = rep * NB;

  const int dil = (stage==0)?1:(stage==1)?3:(stage==2)?6:12;
  const int KIN = (stage==0)?64:96;
  const int K   = KIN + 64;
  const float* Wl = (stage==0)?W0:(stage==1)?W1:(stage==2)?W2:W3;
  const float* bl = (stage==0)?b0:(stage==1)?b1:(stage==2)?b2:b3;

  __shared__ __align__(16) ushort xh_hi[16*XS], xh_lo[16*XS];  // A-operand planes
  __shared__ __align__(16) float  sh_c[12*128*CSTR];           // c ring [slot][sidx][12]
  __shared__ __align__(16) ushort h_hi[12*NB*32], h_lo[12*NB*32]; // h ring planes
  __shared__ __align__(16) ushort outp[2304];  // [hi 768][lo 768] (+pad for proj overread)
  __shared__ __align__(16) ushort o1p[1536];   // stage3: out1 planes [hi 768][lo 768]
  __shared__ __align__(16) float  o3f[NB*OUTC];// stage3: out3 fp32

  for (int i = tid; i < 16*XS; i += 512){ xh_hi[i] = 0; xh_lo[i] = 0; }
  for (int i = tid; i < 12*128*CSTR; i += 512) sh_c[i] = 0.0f;
  for (int i = tid; i < 12*NB*32; i += 512){ h_hi[i] = 0; h_lo[i] = 0; }
  for (int i = tid; i < 2304; i += 512) outp[i] = 0;
  for (int i = tid; i < 1536; i += 512) o1p[i] = 0;
  for (int i = tid; i < NB*OUTC; i += 512) o3f[i] = 0.0f;

  const int sidx = 16*wv + l15;  // state index 0..127 owned by this lane

  // Layer weights as split-bf16 MFMA B-fragments (zero-padded past K).
  bf16x8 whi[4][5], wlo[4][5];
  #pragma unroll
  for (int j = 0; j < 4; ++j){
    const int grow = 128*j + sidx;
    #pragma unroll
    for (int ks = 0; ks < 5; ++ks){
      bf16x8 vh, vl;
      const int cb = ks*32 + hi*8;
      if (cb < K){
        const float* p = Wl + (size_t)grow*K + cb;
        #pragma unroll
        for (int i = 0; i < 8; ++i){
          float w = p[i];
          ushort h = f2bf(w);
          vh[i] = (short)h;
          vl[i] = (short)f2bf(w - bf2f(h));
        }
      } else {
        #pragma unroll
        for (int i = 0; i < 8; ++i){ vh[i] = 0; vl[i] = 0; }
      }
      whi[j][ks] = vh; wlo[j][ks] = vl;
    }
  }
  float bias[4];
  #pragma unroll
  for (int j = 0; j < 4; ++j) bias[j] = bl[128*j + sidx];

  // Projection weights (stage3, waves 0..3)
  bf16x8 phi[3], plo[3];
  #pragma unroll
  for (int ks = 0; ks < 3; ++ks){
    bf16x8 z;
    #pragma unroll
    for (int i = 0; i < 8; ++i) z[i]=0;
    phi[ks]=z; plo[ks]=z;
  }
  float bav = 0.0f;
  if (stage == 3 && wv < 4){
    const int ocol = 16*wv + l15;
    #pragma unroll
    for (int ks = 0; ks < 3; ++ks){
      const float* p = Wa + (size_t)ocol*96 + ks*32 + hi*8;
      bf16x8 vh, vl;
      #pragma unroll
      for (int i = 0; i < 8; ++i){
        float w = p[i];
        ushort h = f2bf(w);
        vh[i] = (short)h;
        vl[i] = (short)f2bf(w - bf2f(h));
      }
      phi[ks] = vh; plo[ks] = vl;
    }
    bav = ba[ocol];
  }

  // Flag wiring
  uint* up_prod  = (stage==1)? &prod[rep] : (stage==2)? &prod[64+rep] :
                   (stage==3)? &prod[128+rep] : nullptr;
  uint* up_prod1 = (stage==3)? &prod[64+rep] : nullptr;        // stage3 also needs hop1
  uint* my_prod  = (stage==0)? &prod[rep] : (stage==1)? &prod[64+rep] :
                   (stage==2)? &prod[128+rep] : nullptr;
  uint* my_consA = (stage==1)? &consA[rep] : (stage==2)? &consA[64+rep] :
                   (stage==3)? &consA[128+rep] : nullptr;
  uint* my_consB = (stage==3)? &consB[rep] : nullptr;
  uint* dnA      = (stage==0)? &consA[rep] : (stage==1)? &consA[64+rep] :
                   (stage==2)? &consA[128+rep] : nullptr;
  uint* dnB      = (stage==1)? &consB[rep] : nullptr;
  const u64* hop_in  = (stage==1)? hop0 : (stage==2)? hop1 : nullptr;
  u64*       hop_out = (stage==0)? hop0 : (stage==1)? hop1 : (stage==2)? hop2 : nullptr;

  __syncthreads();

  // ---- pre-loop prefetch for t = 0 ----
  u64 pfA = 0, pfB = 0; float xv = 0.0f;
  if (stage == 0){
    const int r = tid >> 6, c = tid & 63;
    xv = x[(size_t)(b0r + r)*64 + c];
  } else if (stage < 3){
    uint f = aload32(up_prod);
    while (f < 1u){ __builtin_amdgcn_s_sleep(2); f = aload32(up_prod); }
    if (tid < 384) pfA = aload64(hop_in + (size_t)rep*384 + tid);
  } else {
    uint f = aload32(up_prod);
    while (f < 1u){ __builtin_amdgcn_s_sleep(2); f = aload32(up_prod); }
    f = aload32(up_prod1);
    while (f < 1u){ __builtin_amdgcn_s_sleep(2); f = aload32(up_prod1); }
    const u64* s2 = hop2 + (size_t)rep*384;
    const u64* s1 = hop1 + (size_t)rep*384;
    pfA = (tid < 384) ? aload64(s2 + tid) : aload64(s1 + (tid - 384));
    if (tid < 256) pfB = aload64(s1 + 128 + tid);
  }

  int cur = 0, prv = dil - 1;
  for (int t = 0; t < T_STEPS; ++t){
    const int slot = t & (RD-1);

    // ---- preamble: drain (prefetch loads + prior hop stores), stage to LDS ----
    asm volatile("s_waitcnt vmcnt(0)" ::: "memory");
    if (stage == 0){
      const int r = tid >> 6, c = tid & 63;
      ushort hb = f2bf(xv);
      xh_hi[r*XS + c] = hb;
      xh_lo[r*XS + c] = f2bf(xv - bf2f(hb));
    } else {
      if (tid < 384){
        const int q = (tid < 192) ? tid : tid - 192;
        ushort* plane = (tid < 192) ? xh_hi : xh_lo;
        const int r = q / 24, c4 = (q % 24) * 4;
        *(u64*)(plane + r*XS + c4) = pfA;
      } else if (stage == 3){
        *(u64*)(o1p + 4*(tid - 384)) = pfA;
      }
      if (stage == 3 && tid < 256) *(u64*)(o1p + 4*(128 + tid)) = pfB;
    }
    // h-copy: prev_h -> cols [KIN,KIN+32), del_h -> cols [KIN+32,KIN+64)
    {
      const int which = tid >> 8, rem = tid & 255, r = rem >> 5, c = rem & 31;
      const int srcslot = (which == 1 && t >= dil) ? cur : prv;
      xh_hi[r*XS + KIN + which*32 + c] = h_hi[srcslot*(NB*32) + r*32 + c];
      xh_lo[r*XS + KIN + which*32 + c] = h_lo[srcslot*(NB*32) + r*32 + c];
    }
    __syncthreads();   // B1
    if (tid == 0){
      if (stage > 0){
        astore32(my_consA, (uint)(t+1));
        if (stage == 3) astore32(my_consB, (uint)(t+1));
      }
      if (stage < 3 && t > 0) astore32(my_prod, (uint)t);   // steps <= t-1 drained
    }
    // early flag loads (results consumed much later -> latency hidden)
    const bool pre = (t + 1 < T_STEPS);
    uint up_f = 0, up_f1 = 0, dn_f = 0, dn_fB = 0;
    if (pre && stage > 0)  up_f  = aload32(up_prod);
    if (pre && stage == 3) up_f1 = aload32(up_prod1);
    if (stage < 3)         dn_f  = aload32(dnA);
    if (stage == 1)        dn_fB = aload32(dnB);

    // ---- GEMM: g = xh @ W^T + b  (pure ds_read + MFMA) ----
    f32x4 acc[4];
    #pragma unroll
    for (int j = 0; j < 4; ++j) acc[j] = (f32x4){bias[j],bias[j],bias[j],bias[j]};
    const int abase = l15*XS + hi*8;
    #pragma unroll
    for (int ks = 0; ks < 5; ++ks){
      if (ks*32 < K){
        bf16x8 ahi = *(const bf16x8*)(xh_hi + abase + ks*32);
        bf16x8 alo = *(const bf16x8*)(xh_lo + abase + ks*32);
        #pragma unroll
        for (int j = 0; j < 4; ++j){
          acc[j] = __builtin_amdgcn_mfma_f32_16x16x32_bf16(ahi, whi[j][ks], acc[j], 0, 0, 0);
          acc[j] = __builtin_amdgcn_mfma_f32_16x16x32_bf16(alo, whi[j][ks], acc[j], 0, 0, 0);
          acc[j] = __builtin_amdgcn_mfma_f32_16x16x32_bf16(ahi, wlo[j][ks], acc[j], 0, 0, 0);
        }
      }
    }

    // ---- prefetch data for t+1 (latency hidden under gates + stores) ----
    if (pre){
      if (stage == 0){
        const int r = tid >> 6, c = tid & 63;
        xv = x[(size_t)((t+1)*BATCH + b0r + r)*64 + c];
      } else {
        const uint need = (uint)(t + 2);
        while (up_f < need){ __builtin_amdgcn_s_sleep(2); up_f = aload32(up_prod); }
        if (stage == 3)
          while (up_f1 < need){ __builtin_amdgcn_s_sleep(2); up_f1 = aload32(up_prod1); }
        const int ns = (t + 1) & (RD-1);
        if (stage < 3){
          if (tid < 384) pfA = aload64(hop_in + (size_t)(ns*64 + rep)*384 + tid);
        } else {
          const u64* s2 = hop2 + (size_t)(ns*64 + rep)*384;
          const u64* s1 = hop1 + (size_t)(ns*64 + rep)*384;
          pfA = (tid < 384) ? aload64(s2 + tid) : aload64(s1 + (tid - 384));
          if (tid < 256) pfB = aload64(s1 + 128 + tid);
        }
      }
    }

    // ---- gates + state update (lane owns state sidx, rows hi*4..hi*4+3) ----
    f32x4 pc = *(const f32x4*)(sh_c + prv*(128*CSTR) + sidx*CSTR + hi*4);
    f32x4 dc = *(const f32x4*)(sh_c + cur*(128*CSTR) + sidx*CSTR + hi*4);
    const bool has_prev = (t >= 1), has_del = (t >= dil);
    f32x4 ncv; float whv[4];
    #pragma unroll
    for (int k = 0; k < 4; ++k){
      float f  = sigm(acc[0][k] + 1.0f);
      float cd = tanh_fast(acc[1][k]);
      float al = sigm(acc[2][k]);
      float og = sigm(acc[3][k]);
      float wt = has_del ? (al*pc[k] + (1.0f - al)*dc[k]) : pc[k];
      float nc = has_prev ? (f*wt + (1.0f - f)*cd) : cd;
      ncv[k] = nc;
      whv[k] = og * nc;
    }
    if (hi < 2){
      *(f32x4*)(sh_c + cur*(128*CSTR) + sidx*CSTR + hi*4) = ncv;
      #pragma unroll
      for (int k = 0; k < 4; ++k){
        const int r = hi*4 + k;
        const float w = whv[k];
        if (sidx < OUTC){
          if (stage == 3){
            o3f[r*OUTC + sidx] = w;
          } else {
            ushort hb = f2bf(w);
            outp[r*OUTC + sidx]       = hb;
            outp[768 + r*OUTC + sidx] = f2bf(w - bf2f(hb));
          }
        } else {
          ushort hb = f2bf(w);
          h_hi[cur*(NB*32) + r*32 + (sidx - OUTC)] = hb;
          h_lo[cur*(NB*32) + r*32 + (sidx - OUTC)] = f2bf(w - bf2f(hb));
        }
      }
    }
    __syncthreads();   // B2

    // ---- stage output ----
    if (stage < 3){
      if (t >= RD){
        const uint need = (uint)(t - RD + 1);
        while (dn_f < need){ __builtin_amdgcn_s_sleep(2); dn_f = aload32(dnA); }
        if (stage == 1)
          while (dn_fB < need){ __builtin_amdgcn_s_sleep(2); dn_fB = aload32(dnB); }
      }
      if (tid < 384){
        u64 v = *(const u64*)(outp + 4*tid);
        astore64(hop_out + (size_t)(slot*64 + rep)*384 + tid, v);   // fire & forget
      }
    } else {
      // resnet: pb = out3 + out1 -> PA planes in outp
      for (int j = tid; j < 768; j += 512){
        float v = o3f[j] + bf2f(o1p[j]) + bf2f(o1p[768 + j]);
        ushort hb = f2bf(v);
        outp[j]       = hb;
        outp[768 + j] = f2bf(v - bf2f(hb));
      }
      __syncthreads(); // B3
      if (wv < 4){
        f32x4 acc1 = (f32x4){bav, bav, bav, bav};
        const int pbase = l15*96 + hi*8;
        #pragma unroll
        for (int ks = 0; ks < 3; ++ks){
          bf16x8 ahi = *(const bf16x8*)(outp + pbase + ks*32);
          bf16x8 alo = *(const bf16x8*)(outp + 768 + pbase + ks*32);
          acc1 = __builtin_amdgcn_mfma_f32_16x16x32_bf16(ahi, phi[ks], acc1, 0, 0, 0);
          acc1 = __builtin_amdgcn_mfma_f32_16x16x32_bf16(alo, phi[ks], acc1, 0, 0, 0);
          acc1 = __builtin_amdgcn_mfma_f32_16x16x32_bf16(ahi, plo[ks], acc1, 0, 0, 0);
        }
        if (hi < 2){
          const int ocol = 16*wv + l15;
          #pragma unroll
          for (int k = 0; k < 4; ++k){
            const int r = hi*4 + k;
            y_out[(size_t)(t*BATCH + b0r + r)*64 + ocol] = acc1[k];  // fire & forget
          }
        }
      }
    }
    prv = cur;
    cur = (cur + 1 == dil) ? 0 : cur + 1;
  }

  // final drain + terminal flag (lets consumers' last prefetch complete)
  asm volatile("s_waitcnt vmcnt(0)" ::: "memory");
  __syncthreads();
  if (stage < 3 && tid == 0) astore32(my_prod, (uint)(T_STEPS + 2));
}

extern "C" void kernel_launch(void* const* d_in, const int* in_sizes, int n_in,
                              void* d_out, int out_size, void* d_ws, size_t ws_size,
                              hipStream_t stream) {
  (void)in_sizes; (void)n_in; (void)out_size; (void)ws_size;
  const float* x  = (const float*)d_in[0];
  const float* W0 = (const float*)d_in[1];
  const float* b0 = (const float*)d_in[2];
  const float* W1 = (const float*)d_in[3];
  const float* b1 = (const float*)d_in[4];
  const float* W2 = (const float*)d_in[5];
  const float* b2 = (const float*)d_in[6];
  const float* W3 = (const float*)d_in[7];
  const float* b3 = (const float*)d_in[8];
  const float* Wa = (const float*)d_in[9];
  const float* ba = (const float*)d_in[10];
  float* out = (float*)d_out;

  uint* prod  = (uint*)d_ws;         // [3][64]
  uint* consA = prod + 192;          // [3][64]
  uint* consB = consA + 192;         // [64]
  u64* hop0 = (u64*)((char*)d_ws + 4096);   // [RD][64][384] u64 (hi/lo planes)
  u64* hop1 = hop0 + (size_t)RD*64*384;
  u64* hop2 = hop1 + (size_t)RD*64*384;

  hipMemsetAsync(d_ws, 0, 4096, stream);  // re-zero flags every call
  hipLaunchKernelGGL(rnn_pipeline, dim3(256), dim3(512), 0, stream,
                     x, W0, b0, W1, b1, W2, b2, W3, b3, Wa, ba,
                     out, prod, consA, consB, hop0, hop1, hop2);
}

// Round 6
// 2200.291 us; speedup vs baseline: 1.2307x; 1.2307x over previous
//
#include <hip/hip_runtime.h>

typedef unsigned int uint;
typedef unsigned short ushort;
typedef unsigned long long u64;
typedef __attribute__((ext_vector_type(8))) short bf16x8;
typedef __attribute__((ext_vector_type(4))) float f32x4;

// Problem constants
#define T_STEPS 512
#define BATCH   512
#define NB      8       // batch rows per replica
#define RD      16      // inter-stage ring depth (power of 2)
#define XS      168     // xh plane row stride (ushort)
#define CSTR    12      // c-ring pad: floats per (slot,sidx) row
#define OUTC    96
#define FSTR    32      // flag stride in uints (128B line per flag)

__device__ __forceinline__ ushort f2bf(float f){
  uint u = __builtin_bit_cast(uint, f);
  u = (u + 0x7FFFu + ((u >> 16) & 1u)) >> 16;   // RNE
  return (ushort)u;
}
__device__ __forceinline__ float bf2f(ushort h){
  uint u = ((uint)h) << 16; return __builtin_bit_cast(float, u);
}
__device__ __forceinline__ float sigm(float x){
  float e = __builtin_exp2f(-1.44269504f * x);
  return __builtin_amdgcn_rcpf(1.0f + e);
}
__device__ __forceinline__ float tanh_fast(float x){
  float e = __builtin_exp2f(-2.88539008f * x);
  return 2.0f * __builtin_amdgcn_rcpf(1.0f + e) - 1.0f;
}
// Relaxed agent-scope atomics: LLC-coherent, no L1/L2 invalidate/writeback.
__device__ __forceinline__ uint aload32(const uint* p){
  return __hip_atomic_load(p, __ATOMIC_RELAXED, __HIP_MEMORY_SCOPE_AGENT);
}
__device__ __forceinline__ void astore32(uint* p, uint v){
  __hip_atomic_store(p, v, __ATOMIC_RELAXED, __HIP_MEMORY_SCOPE_AGENT);
}
__device__ __forceinline__ u64 aload64(const u64* p){
  return __hip_atomic_load(p, __ATOMIC_RELAXED, __HIP_MEMORY_SCOPE_AGENT);
}
__device__ __forceinline__ void astore64(u64* p, u64 v){
  __hip_atomic_store(p, v, __ATOMIC_RELAXED, __HIP_MEMORY_SCOPE_AGENT);
}

// 4-stage pipeline (stage = blockIdx.x>>6, rep = blockIdx.x&63), NB=8 rows/block.
// Activations/hops carried as split-bf16 hi/lo planes (converted ONCE by the
// producer); GEMM inner loop is pure ds_read_b128 + MFMA. Hop payloads are
// prefetched into registers one step ahead; producer flags deferred to next
// step's B1 where one vmcnt(0) drains both prefetch loads and hop stores.
// launch_bounds(512,1): weights MUST stay VGPR-resident (128-cap caused
// per-step scratch reloads in rounds 1-5).
__global__ __launch_bounds__(512, 1)
void rnn_pipeline(const float* __restrict__ x,
                  const float* __restrict__ W0, const float* __restrict__ b0,
                  const float* __restrict__ W1, const float* __restrict__ b1,
                  const float* __restrict__ W2, const float* __restrict__ b2,
                  const float* __restrict__ W3, const float* __restrict__ b3,
                  const float* __restrict__ Wa, const float* __restrict__ ba,
                  float* __restrict__ y_out,
                  uint* __restrict__ prod, uint* __restrict__ consA,
                  uint* __restrict__ consB,
                  u64* __restrict__ hop0, u64* __restrict__ hop1,
                  u64* __restrict__ hop2)
{
  const int tid  = threadIdx.x;
  const int wv   = tid >> 6;      // wave 0..7
  const int lane = tid & 63;
  const int l15  = lane & 15;
  const int hi   = lane >> 4;     // 0..3
  const int rep  = blockIdx.x & 63;
  const int stage= blockIdx.x >> 6;
  const int b0r  = rep * NB;

  const int dil = (stage==0)?1:(stage==1)?3:(stage==2)?6:12;
  const int KIN = (stage==0)?64:96;
  const int K   = KIN + 64;
  const float* Wl = (stage==0)?W0:(stage==1)?W1:(stage==2)?W2:W3;
  const float* bl = (stage==0)?b0:(stage==1)?b1:(stage==2)?b2:b3;

  __shared__ __align__(16) ushort xh_hi[16*XS], xh_lo[16*XS];  // A-operand planes
  __shared__ __align__(16) float  sh_c[12*128*CSTR];           // c ring [slot][sidx][12]
  __shared__ __align__(16) ushort h_hi[12*NB*32], h_lo[12*NB*32]; // h ring planes
  __shared__ __align__(16) ushort outp[2304];  // [hi 768][lo 768] (+pad for proj overread)
  __shared__ __align__(16) ushort o1p[1536];   // stage3: out1 planes [hi 768][lo 768]
  __shared__ __align__(16) float  o3f[NB*OUTC];// stage3: out3 fp32

  for (int i = tid; i < 16*XS; i += 512){ xh_hi[i] = 0; xh_lo[i] = 0; }
  for (int i = tid; i < 12*128*CSTR; i += 512) sh_c[i] = 0.0f;
  for (int i = tid; i < 12*NB*32; i += 512){ h_hi[i] = 0; h_lo[i] = 0; }
  for (int i = tid; i < 2304; i += 512) outp[i] = 0;
  for (int i = tid; i < 1536; i += 512) o1p[i] = 0;
  for (int i = tid; i < NB*OUTC; i += 512) o3f[i] = 0.0f;

  const int sidx = 16*wv + l15;  // state index 0..127 owned by this lane

  // Layer weights as split-bf16 MFMA B-fragments (zero-padded past K).
  bf16x8 whi[4][5], wlo[4][5];
  #pragma unroll
  for (int j = 0; j < 4; ++j){
    const int grow = 128*j + sidx;
    #pragma unroll
    for (int ks = 0; ks < 5; ++ks){
      bf16x8 vh, vl;
      const int cb = ks*32 + hi*8;
      if (cb < K){
        const float* p = Wl + (size_t)grow*K + cb;
        #pragma unroll
        for (int i = 0; i < 8; ++i){
          float w = p[i];
          ushort h = f2bf(w);
          vh[i] = (short)h;
          vl[i] = (short)f2bf(w - bf2f(h));
        }
      } else {
        #pragma unroll
        for (int i = 0; i < 8; ++i){ vh[i] = 0; vl[i] = 0; }
      }
      whi[j][ks] = vh; wlo[j][ks] = vl;
    }
  }
  float bias[4];
  #pragma unroll
  for (int j = 0; j < 4; ++j) bias[j] = bl[128*j + sidx];

  // Projection weights (stage3, waves 0..3)
  bf16x8 phi[3], plo[3];
  #pragma unroll
  for (int ks = 0; ks < 3; ++ks){
    bf16x8 z;
    #pragma unroll
    for (int i = 0; i < 8; ++i) z[i]=0;
    phi[ks]=z; plo[ks]=z;
  }
  float bav = 0.0f;
  if (stage == 3 && wv < 4){
    const int ocol = 16*wv + l15;
    #pragma unroll
    for (int ks = 0; ks < 3; ++ks){
      const float* p = Wa + (size_t)ocol*96 + ks*32 + hi*8;
      bf16x8 vh, vl;
      #pragma unroll
      for (int i = 0; i < 8; ++i){
        float w = p[i];
        ushort h = f2bf(w);
        vh[i] = (short)h;
        vl[i] = (short)f2bf(w - bf2f(h));
      }
      phi[ks] = vh; plo[ks] = vl;
    }
    bav = ba[ocol];
  }

  // Flag wiring (each flag on its own 128B line)
  uint* up_prod  = (stage==1)? &prod[rep*FSTR] : (stage==2)? &prod[(64+rep)*FSTR] :
                   (stage==3)? &prod[(128+rep)*FSTR] : nullptr;
  uint* up_prod1 = (stage==3)? &prod[(64+rep)*FSTR] : nullptr;  // stage3 also needs hop1
  uint* my_prod  = (stage==0)? &prod[rep*FSTR] : (stage==1)? &prod[(64+rep)*FSTR] :
                   (stage==2)? &prod[(128+rep)*FSTR] : nullptr;
  uint* my_consA = (stage==1)? &consA[rep*FSTR] : (stage==2)? &consA[(64+rep)*FSTR] :
                   (stage==3)? &consA[(128+rep)*FSTR] : nullptr;
  uint* my_consB = (stage==3)? &consB[rep*FSTR] : nullptr;
  uint* dnA      = (stage==0)? &consA[rep*FSTR] : (stage==1)? &consA[(64+rep)*FSTR] :
                   (stage==2)? &consA[(128+rep)*FSTR] : nullptr;
  uint* dnB      = (stage==1)? &consB[rep*FSTR] : nullptr;
  const u64* hop_in  = (stage==1)? hop0 : (stage==2)? hop1 : nullptr;
  u64*       hop_out = (stage==0)? hop0 : (stage==1)? hop1 : (stage==2)? hop2 : nullptr;

  __syncthreads();

  // ---- pre-loop prefetch for t = 0 ----
  u64 pfA = 0, pfB = 0; float xv = 0.0f;
  if (stage == 0){
    const int r = tid >> 6, c = tid & 63;
    xv = x[(size_t)(b0r + r)*64 + c];
  } else if (stage < 3){
    uint f = aload32(up_prod);
    while (f < 1u){ __builtin_amdgcn_s_sleep(2); f = aload32(up_prod); }
    if (tid < 384) pfA = aload64(hop_in + (size_t)rep*384 + tid);
  } else {
    uint f = aload32(up_prod);
    while (f < 1u){ __builtin_amdgcn_s_sleep(2); f = aload32(up_prod); }
    f = aload32(up_prod1);
    while (f < 1u){ __builtin_amdgcn_s_sleep(2); f = aload32(up_prod1); }
    const u64* s2 = hop2 + (size_t)rep*384;
    const u64* s1 = hop1 + (size_t)rep*384;
    pfA = (tid < 384) ? aload64(s2 + tid) : aload64(s1 + (tid - 384));
    if (tid < 256) pfB = aload64(s1 + 128 + tid);
  }

  int cur = 0, prv = dil - 1;
  for (int t = 0; t < T_STEPS; ++t){
    const int slot = t & (RD-1);

    // ---- preamble: drain (prefetch loads + prior hop stores), stage to LDS ----
    asm volatile("s_waitcnt vmcnt(0)" ::: "memory");
    if (stage == 0){
      const int r = tid >> 6, c = tid & 63;
      ushort hb = f2bf(xv);
      xh_hi[r*XS + c] = hb;
      xh_lo[r*XS + c] = f2bf(xv - bf2f(hb));
    } else {
      if (tid < 384){
        const int q = (tid < 192) ? tid : tid - 192;
        ushort* plane = (tid < 192) ? xh_hi : xh_lo;
        const int r = q / 24, c4 = (q % 24) * 4;
        *(u64*)(plane + r*XS + c4) = pfA;
      } else if (stage == 3){
        *(u64*)(o1p + 4*(tid - 384)) = pfA;
      }
      if (stage == 3 && tid < 256) *(u64*)(o1p + 4*(128 + tid)) = pfB;
    }
    // h-copy: prev_h -> cols [KIN,KIN+32), del_h -> cols [KIN+32,KIN+64)
    {
      const int which = tid >> 8, rem = tid & 255, r = rem >> 5, c = rem & 31;
      const int srcslot = (which == 1 && t >= dil) ? cur : prv;
      xh_hi[r*XS + KIN + which*32 + c] = h_hi[srcslot*(NB*32) + r*32 + c];
      xh_lo[r*XS + KIN + which*32 + c] = h_lo[srcslot*(NB*32) + r*32 + c];
    }
    __syncthreads();   // B1
    if (tid == 0){
      if (stage > 0){
        astore32(my_consA, (uint)(t+1));
        if (stage == 3) astore32(my_consB, (uint)(t+1));
      }
      if (stage < 3 && t > 0) astore32(my_prod, (uint)t);   // steps <= t-1 drained
    }
    // early flag loads (results consumed much later -> latency hidden)
    const bool pre = (t + 1 < T_STEPS);
    uint up_f = 0, up_f1 = 0, dn_f = 0, dn_fB = 0;
    if (pre && stage > 0)  up_f  = aload32(up_prod);
    if (pre && stage == 3) up_f1 = aload32(up_prod1);
    if (stage < 3)         dn_f  = aload32(dnA);
    if (stage == 1)        dn_fB = aload32(dnB);

    // ---- GEMM: g = xh @ W^T + b  (pure ds_read + MFMA) ----
    f32x4 acc[4];
    #pragma unroll
    for (int j = 0; j < 4; ++j) acc[j] = (f32x4){bias[j],bias[j],bias[j],bias[j]};
    const int abase = l15*XS + hi*8;
    #pragma unroll
    for (int ks = 0; ks < 5; ++ks){
      if (ks*32 < K){
        bf16x8 ahi = *(const bf16x8*)(xh_hi + abase + ks*32);
        bf16x8 alo = *(const bf16x8*)(xh_lo + abase + ks*32);
        #pragma unroll
        for (int j = 0; j < 4; ++j){
          acc[j] = __builtin_amdgcn_mfma_f32_16x16x32_bf16(ahi, whi[j][ks], acc[j], 0, 0, 0);
          acc[j] = __builtin_amdgcn_mfma_f32_16x16x32_bf16(alo, whi[j][ks], acc[j], 0, 0, 0);
          acc[j] = __builtin_amdgcn_mfma_f32_16x16x32_bf16(ahi, wlo[j][ks], acc[j], 0, 0, 0);
        }
      }
    }

    // ---- prefetch data for t+1 (latency hidden under gates + stores) ----
    if (pre){
      if (stage == 0){
        const int r = tid >> 6, c = tid & 63;
        xv = x[(size_t)((t+1)*BATCH + b0r + r)*64 + c];
      } else {
        const uint need = (uint)(t + 2);
        while (up_f < need){ __builtin_amdgcn_s_sleep(2); up_f = aload32(up_prod); }
        if (stage == 3)
          while (up_f1 < need){ __builtin_amdgcn_s_sleep(2); up_f1 = aload32(up_prod1); }
        const int ns = (t + 1) & (RD-1);
        if (stage < 3){
          if (tid < 384) pfA = aload64(hop_in + (size_t)(ns*64 + rep)*384 + tid);
        } else {
          const u64* s2 = hop2 + (size_t)(ns*64 + rep)*384;
          const u64* s1 = hop1 + (size_t)(ns*64 + rep)*384;
          pfA = (tid < 384) ? aload64(s2 + tid) : aload64(s1 + (tid - 384));
          if (tid < 256) pfB = aload64(s1 + 128 + tid);
        }
      }
    }

    // ---- gates + state update (lane owns state sidx, rows hi*4..hi*4+3) ----
    f32x4 pc = *(const f32x4*)(sh_c + prv*(128*CSTR) + sidx*CSTR + hi*4);
    f32x4 dc = *(const f32x4*)(sh_c + cur*(128*CSTR) + sidx*CSTR + hi*4);
    const bool has_prev = (t >= 1), has_del = (t >= dil);
    f32x4 ncv; float whv[4];
    #pragma unroll
    for (int k = 0; k < 4; ++k){
      float f  = sigm(acc[0][k] + 1.0f);
      float cd = tanh_fast(acc[1][k]);
      float al = sigm(acc[2][k]);
      float og = sigm(acc[3][k]);
      float wt = has_del ? (al*pc[k] + (1.0f - al)*dc[k]) : pc[k];
      float nc = has_prev ? (f*wt + (1.0f - f)*cd) : cd;
      ncv[k] = nc;
      whv[k] = og * nc;
    }
    if (hi < 2){
      *(f32x4*)(sh_c + cur*(128*CSTR) + sidx*CSTR + hi*4) = ncv;
      #pragma unroll
      for (int k = 0; k < 4; ++k){
        const int r = hi*4 + k;
        const float w = whv[k];
        if (sidx < OUTC){
          if (stage == 3){
            o3f[r*OUTC + sidx] = w;
          } else {
            ushort hb = f2bf(w);
            outp[r*OUTC + sidx]       = hb;
            outp[768 + r*OUTC + sidx] = f2bf(w - bf2f(hb));
          }
        } else {
          ushort hb = f2bf(w);
          h_hi[cur*(NB*32) + r*32 + (sidx - OUTC)] = hb;
          h_lo[cur*(NB*32) + r*32 + (sidx - OUTC)] = f2bf(w - bf2f(hb));
        }
      }
    }
    __syncthreads();   // B2

    // ---- stage output ----
    if (stage < 3){
      if (t >= RD){
        const uint need = (uint)(t - RD + 1);
        while (dn_f < need){ __builtin_amdgcn_s_sleep(2); dn_f = aload32(dnA); }
        if (stage == 1)
          while (dn_fB < need){ __builtin_amdgcn_s_sleep(2); dn_fB = aload32(dnB); }
      }
      if (tid < 384){
        u64 v = *(const u64*)(outp + 4*tid);
        astore64(hop_out + (size_t)(slot*64 + rep)*384 + tid, v);   // fire & forget
      }
    } else {
      // resnet: pb = out3 + out1 -> PA planes in outp
      for (int j = tid; j < 768; j += 512){
        float v = o3f[j] + bf2f(o1p[j]) + bf2f(o1p[768 + j]);
        ushort hb = f2bf(v);
        outp[j]       = hb;
        outp[768 + j] = f2bf(v - bf2f(hb));
      }
      __syncthreads(); // B3
      if (wv < 4){
        f32x4 acc1 = (f32x4){bav, bav, bav, bav};
        const int pbase = l15*96 + hi*8;
        #pragma unroll
        for (int ks = 0; ks < 3; ++ks){
          bf16x8 ahi = *(const bf16x8*)(outp + pbase + ks*32);
          bf16x8 alo = *(const bf16x8*)(outp + 768 + pbase + ks*32);
          acc1 = __builtin_amdgcn_mfma_f32_16x16x32_bf16(ahi, phi[ks], acc1, 0, 0, 0);
          acc1 = __builtin_amdgcn_mfma_f32_16x16x32_bf16(alo, phi[ks], acc1, 0, 0, 0);
          acc1 = __builtin_amdgcn_mfma_f32_16x16x32_bf16(ahi, plo[ks], acc1, 0, 0, 0);
        }
        if (hi < 2){
          const int ocol = 16*wv + l15;
          #pragma unroll
          for (int k = 0; k < 4; ++k){
            const int r = hi*4 + k;
            y_out[(size_t)(t*BATCH + b0r + r)*64 + ocol] = acc1[k];  // fire & forget
          }
        }
      }
    }
    prv = cur;
    cur = (cur + 1 == dil) ? 0 : cur + 1;
  }

  // final drain + terminal flag (lets consumers' last prefetch complete)
  asm volatile("s_waitcnt vmcnt(0)" ::: "memory");
  __syncthreads();
  if (stage < 3 && tid == 0) astore32(my_prod, (uint)(T_STEPS + 2));
}

extern "C" void kernel_launch(void* const* d_in, const int* in_sizes, int n_in,
                              void* d_out, int out_size, void* d_ws, size_t ws_size,
                              hipStream_t stream) {
  (void)in_sizes; (void)n_in; (void)out_size; (void)ws_size;
  const float* x  = (const float*)d_in[0];
  const float* W0 = (const float*)d_in[1];
  const float* b0 = (const float*)d_in[2];
  const float* W1 = (const float*)d_in[3];
  const float* b1 = (const float*)d_in[4];
  const float* W2 = (const float*)d_in[5];
  const float* b2 = (const float*)d_in[6];
  const float* W3 = (const float*)d_in[7];
  const float* b3 = (const float*)d_in[8];
  const float* Wa = (const float*)d_in[9];
  const float* ba = (const float*)d_in[10];
  float* out = (float*)d_out;

  // Flags: 128B line each. prod[3][64] @0, consA[3][64] @24576, consB[64] @49152.
  uint* prod  = (uint*)d_ws;
  uint* consA = (uint*)((char*)d_ws + 24576);
  uint* consB = (uint*)((char*)d_ws + 49152);
  u64* hop0 = (u64*)((char*)d_ws + 65536);   // [RD][64][384] u64 (hi/lo planes)
  u64* hop1 = hop0 + (size_t)RD*64*384;
  u64* hop2 = hop1 + (size_t)RD*64*384;

  hipMemsetAsync(d_ws, 0, 65536, stream);  // re-zero flags every call
  hipLaunchKernelGGL(rnn_pipeline, dim3(256), dim3(512), 0, stream,
                     x, W0, b0, W1, b1, W2, b2, W3, b3, Wa, ba,
                     out, prod, consA, consB, hop0, hop1, hop2);
}